// Round 1
// baseline (154.516 us; speedup 1.0000x reference)
//
#include <hip/hip_runtime.h>

#define N_NODES_C 10000
#define N_EDGES_C 640000
#define IN_F 128
#define OUT_F 512

// ---------------------------------------------------------------- degree count
__global__ void count_deg_kernel(const int* __restrict__ dst, int* __restrict__ deg, int E) {
    int e = blockIdx.x * blockDim.x + threadIdx.x;
    if (e < E) atomicAdd(&deg[dst[e]], 1);
}

// ---------------------------------------------------------------- exclusive scan (single block)
__global__ void scan_kernel(const int* __restrict__ deg, int* __restrict__ offs, int n) {
    __shared__ int sums[1024];
    int t = threadIdx.x;
    int per = (n + 1023) >> 10;
    int begin = t * per;
    int end = min(begin + per, n);
    int s = 0;
    for (int i = begin; i < end; ++i) s += deg[i];
    sums[t] = s;
    __syncthreads();
    // Hillis-Steele inclusive scan over 1024 thread-chunk sums
    for (int off = 1; off < 1024; off <<= 1) {
        int v = (t >= off) ? sums[t - off] : 0;
        __syncthreads();
        sums[t] += v;
        __syncthreads();
    }
    int excl = (t == 0) ? 0 : sums[t - 1];
    for (int i = begin; i < end; ++i) {
        offs[i] = excl;
        excl += deg[i];
    }
}

// ---------------------------------------------------------------- bin edges by dst
__global__ void fill_kernel(const int* __restrict__ src, const int* __restrict__ dst,
                            const int* __restrict__ offs, int* __restrict__ cursor,
                            int* __restrict__ esrc, int E) {
    int e = blockIdx.x * blockDim.x + threadIdx.x;
    if (e < E) {
        int d = dst[e];
        int p = atomicAdd(&cursor[d], 1);
        esrc[offs[d] + p] = src[e];
    }
}

// ---------------------------------------------------------------- per-node mean aggregation
// one block (128 threads, 1 feature/thread) per node; edge ids staged in LDS
__global__ __launch_bounds__(128) void agg_kernel(const float* __restrict__ x,
                                                  const int* __restrict__ esrc,
                                                  const int* __restrict__ offs,
                                                  const int* __restrict__ deg,
                                                  float* __restrict__ h) {
    __shared__ int se[128];
    int node = blockIdx.x;
    int f = threadIdx.x;
    int d = deg[node];
    int o = offs[node];
    float acc = 0.f;
    for (int base = 0; base < d; base += 128) {
        int m = min(128, d - base);
        if (f < m) se[f] = esrc[o + base + f];
        __syncthreads();
        for (int i = 0; i < m; ++i) {
            acc += x[se[i] * IN_F + f];   // coalesced 512B row read per i
        }
        __syncthreads();
    }
    float outv = (d > 0) ? (acc / (float)d) : x[node * IN_F + f];
    h[node * IN_F + f] = outv;
}

// ---------------------------------------------------------------- GEMM: out[M,512] = h[M,128] @ W[128,512] + b
// block = 256 threads handles 16 rows x 512 cols; h rows staged in LDS,
// W streamed (L2-resident, 256 KB total). Each thread: 2 cols x 16 rows.
__global__ __launch_bounds__(256) void gemm_kernel(const float* __restrict__ h,
                                                   const float* __restrict__ W,
                                                   const float* __restrict__ b,
                                                   float* __restrict__ out, int M) {
    __shared__ float hs[16][IN_F];
    int row0 = blockIdx.x * 16;
    int t = threadIdx.x;
    for (int i = t; i < 16 * IN_F; i += 256) {
        int r = i >> 7, k = i & 127;
        int gr = row0 + r;
        hs[r][k] = (gr < M) ? h[gr * IN_F + k] : 0.f;
    }
    __syncthreads();

    float acc0[16], acc1[16];
#pragma unroll
    for (int r = 0; r < 16; ++r) { acc0[r] = 0.f; acc1[r] = 0.f; }

    int c = t;  // columns c and c+256
#pragma unroll 4
    for (int k = 0; k < IN_F; ++k) {
        float w0 = W[k * OUT_F + c];
        float w1 = W[k * OUT_F + c + 256];
#pragma unroll
        for (int r = 0; r < 16; ++r) {
            float hv = hs[r][k];
            acc0[r] += hv * w0;
            acc1[r] += hv * w1;
        }
    }

    float b0 = b[c], b1 = b[c + 256];
#pragma unroll
    for (int r = 0; r < 16; ++r) {
        int gr = row0 + r;
        if (gr < M) {
            out[gr * OUT_F + c] = acc0[r] + b0;
            out[gr * OUT_F + c + 256] = acc1[r] + b1;
        }
    }
}

// ---------------------------------------------------------------- launch
extern "C" void kernel_launch(void* const* d_in, const int* in_sizes, int n_in,
                              void* d_out, int out_size, void* d_ws, size_t ws_size,
                              hipStream_t stream) {
    const float* x   = (const float*)d_in[0];
    const int*   src = (const int*)d_in[1];
    const int*   dst = (const int*)d_in[2];
    const float* W   = (const float*)d_in[3];
    const float* b   = (const float*)d_in[4];
    float*       out = (float*)d_out;

    const int N = N_NODES_C;
    const int E = in_sizes[1];  // 640000

    char* ws   = (char*)d_ws;
    float* h   = (float*)ws;                              // N*128 floats (5.12 MB)
    int*  deg  = (int*)(ws + (size_t)N * IN_F * sizeof(float));
    int*  cursor = deg + N;                               // adjacent to deg for one memset
    int*  offs = cursor + N;
    int*  esrc = offs + N;                                // E ints

    // zero deg + cursor (adjacent)
    hipMemsetAsync(deg, 0, 2 * N * sizeof(int), stream);

    count_deg_kernel<<<(E + 255) / 256, 256, 0, stream>>>(dst, deg, E);
    scan_kernel<<<1, 1024, 0, stream>>>(deg, offs, N);
    fill_kernel<<<(E + 255) / 256, 256, 0, stream>>>(src, dst, offs, cursor, esrc, E);
    agg_kernel<<<N, 128, 0, stream>>>(x, esrc, offs, deg, h);
    gemm_kernel<<<(N + 15) / 16, 256, 0, stream>>>(h, W, b, out, N);
}